// Round 1
// baseline (1060.816 us; speedup 1.0000x reference)
//
#include <hip/hip_runtime.h>
#include <hip/hip_bf16.h>

#define N_NODES_C 50000
#define N_EDGES_C 800000
#define N_GRAPHS_C 64

// ---------------- degree ----------------
__global__ void k_deg(const int* __restrict__ dst, float* __restrict__ deg, int nE) {
    int e = blockIdx.x * blockDim.x + threadIdx.x;
    if (e >= nE) return;
    atomicAdd(&deg[dst[e]], 1.0f);
}

__global__ void k_dinv(float* __restrict__ deg, int n) {
    int i = blockIdx.x * blockDim.x + threadIdx.x;
    if (i >= n) return;
    deg[i] = rsqrtf(deg[i] + 1.0f);   // in-place: deg -> dinv
}

// ---------------- dense matmul H = X @ W ----------------
// block = RPB * COUT threads; W cached in LDS.
template<int CIN, int COUT, int RPB>
__global__ void k_mm(const float* __restrict__ X, const float* __restrict__ W,
                     float* __restrict__ H, int n) {
    __shared__ float sW[CIN * COUT];
    __shared__ float sx[RPB][CIN];
    const int tid = threadIdx.x;            // 0 .. RPB*COUT-1
    for (int i = tid; i < CIN * COUT; i += RPB * COUT) sW[i] = W[i];
    for (int i = tid; i < RPB * CIN; i += RPB * COUT) {
        int rr = i / CIN, kk = i % CIN;
        int grow = blockIdx.x * RPB + rr;
        sx[rr][kk] = (grow < n) ? X[grow * CIN + kk] : 0.f;
    }
    __syncthreads();
    const int r = tid / COUT, c = tid % COUT;
    const int row = blockIdx.x * RPB + r;
    if (row >= n) return;
    float acc = 0.f;
#pragma unroll
    for (int k = 0; k < CIN; ++k) acc = fmaf(sx[r][k], sW[k * COUT + c], acc);
    H[row * COUT + c] = acc;
}

// ---------------- self-loop init: AGG = H * dinv^2 ----------------
template<int C>
__global__ void k_selfinit(const float* __restrict__ H, const float* __restrict__ dinv,
                           float* __restrict__ AGG, int n) {
    int i = blockIdx.x * blockDim.x + threadIdx.x;
    if (i >= n * C) return;
    int node = i / C;
    float di = dinv[node];
    AGG[i] = H[i] * di * di;
}

// ---------------- edge scatter: AGG[dst] += H[src] * dinv[src]*dinv[dst] ----------------
template<int C>
__global__ void k_edge_agg(const int* __restrict__ src, const int* __restrict__ dst,
                           const float* __restrict__ dinv, const float* __restrict__ H,
                           float* __restrict__ AGG, int nE) {
    long t = (long)blockIdx.x * blockDim.x + threadIdx.x;
    int e = (int)(t / C);
    int c = (int)(t % C);
    if (e >= nE) return;
    int s = src[e], d = dst[e];
    float norm = dinv[s] * dinv[d];
    atomicAdd(&AGG[(long)d * C + c], H[(long)s * C + c] * norm);
}

// ---------------- bias + relu (in place) ----------------
template<int C>
__global__ void k_bias_relu(float* __restrict__ A, const float* __restrict__ b, int n) {
    int i = blockIdx.x * blockDim.x + threadIdx.x;
    if (i >= n * C) return;
    float v = A[i] + b[i % C];
    A[i] = v > 0.f ? v : 0.f;
}

// ---------------- segment-max pooling (values are >=0 post-ReLU) ----------------
__global__ void k_pool(const float* __restrict__ H, const int* __restrict__ batch,
                       unsigned* __restrict__ P, int n) {
    int i = blockIdx.x * blockDim.x + threadIdx.x;
    if (i >= n * 128) return;
    int nd = i >> 7, c = i & 127;
    atomicMax(&P[batch[nd] * 128 + c], __float_as_uint(H[i]));
}

// ---------------- MLP head + log_softmax: one block, 64 threads (1 graph each) ----------------
__global__ void k_head(const float* __restrict__ P,
                       const float* __restrict__ W3, const float* __restrict__ b3,
                       const float* __restrict__ g3, const float* __restrict__ beta3,
                       const float* __restrict__ W4, const float* __restrict__ b4,
                       const float* __restrict__ g4, const float* __restrict__ beta4,
                       const float* __restrict__ W5, const float* __restrict__ b5,
                       float* __restrict__ out) {
    __shared__ float sP[64 * 129];          // stride 129: conflict-free column reads
    __shared__ float sW3[128 * 32];
    __shared__ float sW4[32 * 64];
    __shared__ float sW5[64 * 10];
    const int tid = threadIdx.x;            // 64 threads
    for (int i = tid; i < 64 * 128; i += 64) sP[(i >> 7) * 129 + (i & 127)] = P[i];
    for (int i = tid; i < 128 * 32; i += 64) sW3[i] = W3[i];
    for (int i = tid; i < 32 * 64; i += 64) sW4[i] = W4[i];
    for (int i = tid; i < 64 * 10; i += 64) sW5[i] = W5[i];
    __syncthreads();

    const float bnscale = rsqrtf(1.0f + 1e-5f);

    float z3[32];
#pragma unroll
    for (int j = 0; j < 32; ++j) {
        float a = 0.f;
#pragma unroll
        for (int k = 0; k < 128; ++k) a = fmaf(sP[tid * 129 + k], sW3[k * 32 + j], a);
        a += b3[j];
        a = a > 0.f ? a : 0.f;
        z3[j] = a * (g3[j] * bnscale) + beta3[j];
    }
    float z4[64];
#pragma unroll
    for (int j = 0; j < 64; ++j) {
        float a = 0.f;
#pragma unroll
        for (int k = 0; k < 32; ++k) a = fmaf(z3[k], sW4[k * 64 + j], a);
        a += b4[j];
        a = a > 0.f ? a : 0.f;
        z4[j] = a * (g4[j] * bnscale) + beta4[j];
    }
    float lg[10];
    float m = -1e30f;
#pragma unroll
    for (int j = 0; j < 10; ++j) {
        float a = 0.f;
#pragma unroll
        for (int k = 0; k < 64; ++k) a = fmaf(z4[k], sW5[k * 10 + j], a);
        a += b5[j];
        lg[j] = a;
        m = fmaxf(m, a);
    }
    float sum = 0.f;
#pragma unroll
    for (int j = 0; j < 10; ++j) sum += expf(lg[j] - m);
    float lse = m + logf(sum);
#pragma unroll
    for (int j = 0; j < 10; ++j) out[tid * 10 + j] = lg[j] - lse;
}

extern "C" void kernel_launch(void* const* d_in, const int* in_sizes, int n_in,
                              void* d_out, int out_size, void* d_ws, size_t ws_size,
                              hipStream_t stream) {
    const float* x        = (const float*)d_in[0];
    const int*   edge_src = (const int*)d_in[1];
    const int*   edge_dst = (const int*)d_in[2];
    const int*   batch    = (const int*)d_in[3];
    const float* W1 = (const float*)d_in[4];
    const float* b1 = (const float*)d_in[5];
    const float* W2 = (const float*)d_in[6];
    const float* b2 = (const float*)d_in[7];
    const float* W3 = (const float*)d_in[8];
    const float* b3 = (const float*)d_in[9];
    const float* g3 = (const float*)d_in[10];
    const float* beta3 = (const float*)d_in[11];
    const float* W4 = (const float*)d_in[12];
    const float* b4 = (const float*)d_in[13];
    const float* g4 = (const float*)d_in[14];
    const float* beta4 = (const float*)d_in[15];
    const float* W5 = (const float*)d_in[16];
    const float* b5 = (const float*)d_in[17];
    float* out = (float*)d_out;

    const int n  = in_sizes[0] / 32;    // 50000
    const int nE = in_sizes[1];         // 800000

    // workspace layout (floats)
    float* ws = (float*)d_ws;
    float* dinv   = ws;                         // 50048 (padded)
    float* h1p    = dinv + 50048;               // n*64  = 3.2M
    float* h1     = h1p + (size_t)n * 64;       // n*64  = 3.2M   (agg1, becomes h1)
    float* h2p    = h1 + (size_t)n * 64;        // n*128 = 6.4M
    float* agg2   = h1p;                        // aliases h1p+h1 after they are dead (6.4M)
    float* pooled = h2p + (size_t)n * 128;      // 64*128 = 8192

    // 0) zero deg + pooled
    hipMemsetAsync(dinv, 0, (size_t)n * sizeof(float), stream);
    hipMemsetAsync(pooled, 0, 64 * 128 * sizeof(float), stream);

    // 1) degree + dinv
    k_deg<<<(nE + 255) / 256, 256, 0, stream>>>(edge_dst, dinv, nE);
    k_dinv<<<(n + 255) / 256, 256, 0, stream>>>(dinv, n);

    // 2) layer 1: 32 -> 64
    k_mm<32, 64, 4><<<(n + 3) / 4, 256, 0, stream>>>(x, W1, h1p, n);
    k_selfinit<64><<<((n * 64) + 255) / 256, 256, 0, stream>>>(h1p, dinv, h1, n);
    k_edge_agg<64><<<((long)nE * 64 + 255) / 256, 256, 0, stream>>>(edge_src, edge_dst, dinv, h1p, h1, nE);
    k_bias_relu<64><<<((n * 64) + 255) / 256, 256, 0, stream>>>(h1, b1, n);

    // 3) layer 2: 64 -> 128
    k_mm<64, 128, 2><<<(n + 1) / 2, 256, 0, stream>>>(h1, W2, h2p, n);
    k_selfinit<128><<<((n * 128) + 255) / 256, 256, 0, stream>>>(h2p, dinv, agg2, n);
    k_edge_agg<128><<<((long)nE * 128 + 255) / 256, 256, 0, stream>>>(edge_src, edge_dst, dinv, h2p, agg2, nE);
    k_bias_relu<128><<<((n * 128) + 255) / 256, 256, 0, stream>>>(agg2, b2, n);

    // 4) segment-max pooling
    k_pool<<<((n * 128) + 255) / 256, 256, 0, stream>>>(agg2, batch, (unsigned*)pooled, n);

    // 5) MLP head + log_softmax
    k_head<<<1, 64, 0, stream>>>(pooled, W3, b3, g3, beta3, W4, b4, g4, beta4, W5, b5, out);
}

// Round 2
// 729.526 us; speedup vs baseline: 1.4541x; 1.4541x over previous
//
#include <hip/hip_runtime.h>
#include <hip/hip_bf16.h>

#define N_NODES_C 50000
#define N_EDGES_C 800000
#define N_GRAPHS_C 64

// ---------------- degree ----------------
__global__ void k_deg(const int* __restrict__ dst, float* __restrict__ deg, int nE) {
    int e = blockIdx.x * blockDim.x + threadIdx.x;
    if (e >= nE) return;
    atomicAdd(&deg[dst[e]], 1.0f);
}

__global__ void k_dinv(float* __restrict__ deg, int n) {
    int i = blockIdx.x * blockDim.x + threadIdx.x;
    if (i >= n) return;
    deg[i] = rsqrtf(deg[i] + 1.0f);   // in-place: deg -> dinv
}

// ---------------- dense matmul H = X @ W, fused AGG = H * dinv^2 ----------------
template<int CIN, int COUT, int RPB>
__global__ void k_mm(const float* __restrict__ X, const float* __restrict__ W,
                     const float* __restrict__ dinv,
                     float* __restrict__ H, float* __restrict__ AGG, int n) {
    __shared__ float sW[CIN * COUT];
    __shared__ float sx[RPB][CIN];
    const int tid = threadIdx.x;            // 0 .. RPB*COUT-1
    for (int i = tid; i < CIN * COUT; i += RPB * COUT) sW[i] = W[i];
    for (int i = tid; i < RPB * CIN; i += RPB * COUT) {
        int rr = i / CIN, kk = i % CIN;
        int grow = blockIdx.x * RPB + rr;
        sx[rr][kk] = (grow < n) ? X[grow * CIN + kk] : 0.f;
    }
    __syncthreads();
    const int r = tid / COUT, c = tid % COUT;
    const int row = blockIdx.x * RPB + r;
    if (row >= n) return;
    float acc = 0.f;
#pragma unroll
    for (int k = 0; k < CIN; ++k) acc = fmaf(sx[r][k], sW[k * COUT + c], acc);
    float di = dinv[row];
    H[row * COUT + c] = acc;
    AGG[row * COUT + c] = acc * di * di;
}

// ---------------- edge scatter: AGG[dst] += H[src] * dinv[src]*dinv[dst] ----------------
template<int C>
__global__ void k_edge_agg(const int* __restrict__ src, const int* __restrict__ dst,
                           const float* __restrict__ dinv, const float* __restrict__ H,
                           float* __restrict__ AGG, int nE) {
    long t = (long)blockIdx.x * blockDim.x + threadIdx.x;
    int e = (int)(t / C);
    int c = (int)(t % C);
    if (e >= nE) return;
    int s = src[e], d = dst[e];
    float norm = dinv[s] * dinv[d];
    atomicAdd(&AGG[(long)d * C + c], H[(long)s * C + c] * norm);
}

// ---------------- bias + relu (in place, layer 1) ----------------
template<int C>
__global__ void k_bias_relu(float* __restrict__ A, const float* __restrict__ b, int n) {
    int i = blockIdx.x * blockDim.x + threadIdx.x;
    if (i >= n * C) return;
    float v = A[i] + b[i % C];
    A[i] = v > 0.f ? v : 0.f;
}

// ---------------- layer2 bias + relu + segment-max pool (no writeback) ----------------
__global__ void k_bias_relu_pool(const float* __restrict__ A, const float* __restrict__ b,
                                 const int* __restrict__ batch, unsigned* __restrict__ P,
                                 int n) {
    int i = blockIdx.x * blockDim.x + threadIdx.x;
    if (i >= n * 128) return;
    int nd = i >> 7, c = i & 127;
    float v = A[i] + b[c];
    v = v > 0.f ? v : 0.f;               // >= 0, so uint-compare == float-compare
    atomicMax(&P[batch[nd] * 128 + c], __float_as_uint(v));
}

// ---------------- MLP head + log_softmax: one block per graph ----------------
__global__ void k_head(const float* __restrict__ P,
                       const float* __restrict__ W3, const float* __restrict__ b3,
                       const float* __restrict__ g3, const float* __restrict__ beta3,
                       const float* __restrict__ W4, const float* __restrict__ b4,
                       const float* __restrict__ g4, const float* __restrict__ beta4,
                       const float* __restrict__ W5, const float* __restrict__ b5,
                       float* __restrict__ out) {
    __shared__ float sP[128];
    __shared__ float sz3[32];
    __shared__ float sz4[64];
    __shared__ float slg[10];
    __shared__ float slse;
    const int g = blockIdx.x, tid = threadIdx.x;   // 128 threads
    sP[tid] = P[g * 128 + tid];
    __syncthreads();
    const float bnscale = rsqrtf(1.0f + 1e-5f);

    if (tid < 32) {
        float a = 0.f;
#pragma unroll
        for (int k = 0; k < 128; ++k) a = fmaf(sP[k], W3[k * 32 + tid], a);
        a += b3[tid];
        a = a > 0.f ? a : 0.f;
        sz3[tid] = a * (g3[tid] * bnscale) + beta3[tid];
    }
    __syncthreads();
    if (tid < 64) {
        float a = 0.f;
#pragma unroll
        for (int k = 0; k < 32; ++k) a = fmaf(sz3[k], W4[k * 64 + tid], a);
        a += b4[tid];
        a = a > 0.f ? a : 0.f;
        sz4[tid] = a * (g4[tid] * bnscale) + beta4[tid];
    }
    __syncthreads();
    if (tid < 10) {
        float a = 0.f;
#pragma unroll
        for (int k = 0; k < 64; ++k) a = fmaf(sz4[k], W5[k * 10 + tid], a);
        slg[tid] = a + b5[tid];
    }
    __syncthreads();
    if (tid == 0) {
        float m = -1e30f;
#pragma unroll
        for (int j = 0; j < 10; ++j) m = fmaxf(m, slg[j]);
        float s = 0.f;
#pragma unroll
        for (int j = 0; j < 10; ++j) s += expf(slg[j] - m);
        slse = m + logf(s);
    }
    __syncthreads();
    if (tid < 10) out[g * 10 + tid] = slg[tid] - slse;
}

extern "C" void kernel_launch(void* const* d_in, const int* in_sizes, int n_in,
                              void* d_out, int out_size, void* d_ws, size_t ws_size,
                              hipStream_t stream) {
    const float* x        = (const float*)d_in[0];
    const int*   edge_src = (const int*)d_in[1];
    const int*   edge_dst = (const int*)d_in[2];
    const int*   batch    = (const int*)d_in[3];
    const float* W1 = (const float*)d_in[4];
    const float* b1 = (const float*)d_in[5];
    const float* W2 = (const float*)d_in[6];
    const float* b2 = (const float*)d_in[7];
    const float* W3 = (const float*)d_in[8];
    const float* b3 = (const float*)d_in[9];
    const float* g3 = (const float*)d_in[10];
    const float* beta3 = (const float*)d_in[11];
    const float* W4 = (const float*)d_in[12];
    const float* b4 = (const float*)d_in[13];
    const float* g4 = (const float*)d_in[14];
    const float* beta4 = (const float*)d_in[15];
    const float* W5 = (const float*)d_in[16];
    const float* b5 = (const float*)d_in[17];
    float* out = (float*)d_out;

    const int n  = in_sizes[0] / 32;    // 50000
    const int nE = in_sizes[1];         // 800000

    // workspace layout (floats)
    float* ws = (float*)d_ws;
    float* dinv   = ws;                         // 50048 (padded)
    float* h1p    = dinv + 50048;               // n*64
    float* h1     = h1p + (size_t)n * 64;       // n*64   (agg1 -> h1)
    float* h2p    = h1 + (size_t)n * 64;        // n*128
    float* agg2   = h1p;                        // aliases h1p+h1 after they are dead
    float* pooled = h2p + (size_t)n * 128;      // 64*128

    // 0) zero deg + pooled
    hipMemsetAsync(dinv, 0, (size_t)n * sizeof(float), stream);
    hipMemsetAsync(pooled, 0, 64 * 128 * sizeof(float), stream);

    // 1) degree + dinv
    k_deg<<<(nE + 255) / 256, 256, 0, stream>>>(edge_dst, dinv, nE);
    k_dinv<<<(n + 255) / 256, 256, 0, stream>>>(dinv, n);

    // 2) layer 1: 32 -> 64  (mm writes H and self-loop-scaled AGG)
    k_mm<32, 64, 4><<<(n + 3) / 4, 256, 0, stream>>>(x, W1, dinv, h1p, h1, n);
    k_edge_agg<64><<<(int)(((long)nE * 64 + 255) / 256), 256, 0, stream>>>(edge_src, edge_dst, dinv, h1p, h1, nE);
    k_bias_relu<64><<<((n * 64) + 255) / 256, 256, 0, stream>>>(h1, b1, n);

    // 3) layer 2: 64 -> 128
    k_mm<64, 128, 2><<<(n + 1) / 2, 256, 0, stream>>>(h1, W2, dinv, h2p, agg2, n);
    k_edge_agg<128><<<(int)(((long)nE * 128 + 255) / 256), 256, 0, stream>>>(edge_src, edge_dst, dinv, h2p, agg2, nE);

    // 4) layer2 bias+relu fused with segment-max pooling (no writeback of h2)
    k_bias_relu_pool<<<((n * 128) + 255) / 256, 256, 0, stream>>>(agg2, b2, batch, (unsigned*)pooled, n);

    // 5) MLP head + log_softmax
    k_head<<<64, 128, 0, stream>>>(pooled, W3, b3, g3, beta3, W4, b4, g4, beta4, W5, b5, out);
}

// Round 3
// 462.952 us; speedup vs baseline: 2.2914x; 1.5758x over previous
//
#include <hip/hip_runtime.h>
#include <hip/hip_bf16.h>

#define N_NODES_C 50000
#define N_EDGES_C 800000
#define N_GRAPHS_C 64

// ---------------- histogram of dst (int counts) ----------------
__global__ void k_hist(const int* __restrict__ dst, int* __restrict__ counts, int nE) {
    int e = blockIdx.x * blockDim.x + threadIdx.x;
    if (e >= nE) return;
    atomicAdd(&counts[dst[e]], 1);
}

__global__ void k_dinv(const int* __restrict__ counts, float* __restrict__ dinv, int n) {
    int i = blockIdx.x * blockDim.x + threadIdx.x;
    if (i >= n) return;
    dinv[i] = rsqrtf((float)counts[i] + 1.0f);
}

// ---------------- 3-kernel exclusive scan over counts -> row ----------------
__global__ void k_scan_block(const int* __restrict__ counts, int* __restrict__ row,
                             int* __restrict__ partial, int n) {
    __shared__ int s[256];
    int i = blockIdx.x * 256 + threadIdx.x;
    int v = (i < n) ? counts[i] : 0;
    s[threadIdx.x] = v;
    __syncthreads();
    for (int off = 1; off < 256; off <<= 1) {
        int x = (threadIdx.x >= off) ? s[threadIdx.x - off] : 0;
        __syncthreads();
        s[threadIdx.x] += x;
        __syncthreads();
    }
    if (i < n) row[i] = s[threadIdx.x] - v;          // exclusive
    if (threadIdx.x == 255) partial[blockIdx.x] = s[255];
}

__global__ void k_scan_partial(int* __restrict__ partial, int m) {
    __shared__ int s[256];
    int v = (threadIdx.x < m) ? partial[threadIdx.x] : 0;
    s[threadIdx.x] = v;
    __syncthreads();
    for (int off = 1; off < 256; off <<= 1) {
        int x = (threadIdx.x >= off) ? s[threadIdx.x - off] : 0;
        __syncthreads();
        s[threadIdx.x] += x;
        __syncthreads();
    }
    if (threadIdx.x < m) partial[threadIdx.x] = s[threadIdx.x] - v;   // exclusive
}

__global__ void k_scan_add(int* __restrict__ row, const int* __restrict__ partial, int n) {
    int i = blockIdx.x * 256 + threadIdx.x;
    if (i < n) row[i] += partial[blockIdx.x];
}

// ---------------- fill CSR: row[d] acts as cursor, ends at row_end ----------------
__global__ void k_fill(const int* __restrict__ src, const int* __restrict__ dst,
                       int* __restrict__ row, int* __restrict__ csr_src, int nE) {
    int e = blockIdx.x * blockDim.x + threadIdx.x;
    if (e >= nE) return;
    int d = dst[e];
    int p = atomicAdd(&row[d], 1);
    csr_src[p] = src[e];
}

// ---------------- dense matmul H = X @ W ----------------
template<int CIN, int COUT, int RPB>
__global__ void k_mm(const float* __restrict__ X, const float* __restrict__ W,
                     float* __restrict__ H, int n) {
    __shared__ float sW[CIN * COUT];
    __shared__ float sx[RPB][CIN];
    const int tid = threadIdx.x;
    for (int i = tid; i < CIN * COUT; i += RPB * COUT) sW[i] = W[i];
    for (int i = tid; i < RPB * CIN; i += RPB * COUT) {
        int rr = i / CIN, kk = i % CIN;
        int grow = blockIdx.x * RPB + rr;
        sx[rr][kk] = (grow < n) ? X[grow * CIN + kk] : 0.f;
    }
    __syncthreads();
    const int r = tid / COUT, c = tid % COUT;
    const int row = blockIdx.x * RPB + r;
    if (row >= n) return;
    float acc = 0.f;
#pragma unroll
    for (int k = 0; k < CIN; ++k) acc = fmaf(sx[r][k], sW[k * COUT + c], acc);
    H[row * COUT + c] = acc;
}

// ---------------- pull aggregation, fused self-loop+bias+relu (+pool) ----------------
// result = dinv[d] * (sum_e H[s]*dinv[s] + H[d]*dinv[d]) + b
template<int C, bool POOL>
__global__ void k_gather(const float* __restrict__ H, const float* __restrict__ dinv,
                         const int* __restrict__ row_end, const int* __restrict__ counts,
                         const int* __restrict__ csr_src, const float* __restrict__ bias,
                         float* __restrict__ OUT, const int* __restrict__ batch,
                         unsigned* __restrict__ P, int n) {
    constexpr int LPN = C / 4;            // lanes per node (float4 per lane)
    constexpr int NPB = 256 / LPN;        // nodes per block
    const int node = blockIdx.x * NPB + threadIdx.x / LPN;
    const int lane = threadIdx.x % LPN;
    if (node >= n) return;
    const int end = row_end[node];
    const int cnt = counts[node];
    const int start = end - cnt;
    const float4* __restrict__ H4 = (const float4*)H;
    const float dd = dinv[node];
    float4 hs = H4[(size_t)node * LPN + lane];
    float4 acc;
    acc.x = hs.x * dd; acc.y = hs.y * dd; acc.z = hs.z * dd; acc.w = hs.w * dd;
    int sN = (cnt > 0) ? csr_src[start] : 0;
    for (int j = start; j < end; ) {
        int s = sN;
        ++j;
        if (j < end) sN = csr_src[j];
        float ds = dinv[s];
        float4 hv = H4[(size_t)s * LPN + lane];
        acc.x = fmaf(hv.x, ds, acc.x);
        acc.y = fmaf(hv.y, ds, acc.y);
        acc.z = fmaf(hv.z, ds, acc.z);
        acc.w = fmaf(hv.w, ds, acc.w);
    }
    float4 bv = ((const float4*)bias)[lane];
    float vx = fmaf(acc.x, dd, bv.x); vx = vx > 0.f ? vx : 0.f;
    float vy = fmaf(acc.y, dd, bv.y); vy = vy > 0.f ? vy : 0.f;
    float vz = fmaf(acc.z, dd, bv.z); vz = vz > 0.f ? vz : 0.f;
    float vw = fmaf(acc.w, dd, bv.w); vw = vw > 0.f ? vw : 0.f;
    if (POOL) {
        int g = batch[node];
        unsigned* p = P + (size_t)g * C + lane * 4;
        atomicMax(p + 0, __float_as_uint(vx));
        atomicMax(p + 1, __float_as_uint(vy));
        atomicMax(p + 2, __float_as_uint(vz));
        atomicMax(p + 3, __float_as_uint(vw));
    } else {
        float4 o; o.x = vx; o.y = vy; o.z = vz; o.w = vw;
        ((float4*)OUT)[(size_t)node * LPN + lane] = o;
    }
}

// ---------------- MLP head + log_softmax: one block per graph ----------------
__global__ void k_head(const float* __restrict__ P,
                       const float* __restrict__ W3, const float* __restrict__ b3,
                       const float* __restrict__ g3, const float* __restrict__ beta3,
                       const float* __restrict__ W4, const float* __restrict__ b4,
                       const float* __restrict__ g4, const float* __restrict__ beta4,
                       const float* __restrict__ W5, const float* __restrict__ b5,
                       float* __restrict__ out) {
    __shared__ float sP[128];
    __shared__ float sz3[32];
    __shared__ float sz4[64];
    __shared__ float slg[10];
    __shared__ float slse;
    const int g = blockIdx.x, tid = threadIdx.x;   // 128 threads
    sP[tid] = P[g * 128 + tid];
    __syncthreads();
    const float bnscale = rsqrtf(1.0f + 1e-5f);

    if (tid < 32) {
        float a = 0.f;
#pragma unroll
        for (int k = 0; k < 128; ++k) a = fmaf(sP[k], W3[k * 32 + tid], a);
        a += b3[tid];
        a = a > 0.f ? a : 0.f;
        sz3[tid] = a * (g3[tid] * bnscale) + beta3[tid];
    }
    __syncthreads();
    if (tid < 64) {
        float a = 0.f;
#pragma unroll
        for (int k = 0; k < 32; ++k) a = fmaf(sz3[k], W4[k * 64 + tid], a);
        a += b4[tid];
        a = a > 0.f ? a : 0.f;
        sz4[tid] = a * (g4[tid] * bnscale) + beta4[tid];
    }
    __syncthreads();
    if (tid < 10) {
        float a = 0.f;
#pragma unroll
        for (int k = 0; k < 64; ++k) a = fmaf(sz4[k], W5[k * 10 + tid], a);
        slg[tid] = a + b5[tid];
    }
    __syncthreads();
    if (tid == 0) {
        float m = -1e30f;
#pragma unroll
        for (int j = 0; j < 10; ++j) m = fmaxf(m, slg[j]);
        float s = 0.f;
#pragma unroll
        for (int j = 0; j < 10; ++j) s += expf(slg[j] - m);
        slse = m + logf(s);
    }
    __syncthreads();
    if (tid < 10) out[g * 10 + tid] = slg[tid] - slse;
}

extern "C" void kernel_launch(void* const* d_in, const int* in_sizes, int n_in,
                              void* d_out, int out_size, void* d_ws, size_t ws_size,
                              hipStream_t stream) {
    const float* x        = (const float*)d_in[0];
    const int*   edge_src = (const int*)d_in[1];
    const int*   edge_dst = (const int*)d_in[2];
    const int*   batch    = (const int*)d_in[3];
    const float* W1 = (const float*)d_in[4];
    const float* b1 = (const float*)d_in[5];
    const float* W2 = (const float*)d_in[6];
    const float* b2 = (const float*)d_in[7];
    const float* W3 = (const float*)d_in[8];
    const float* b3 = (const float*)d_in[9];
    const float* g3 = (const float*)d_in[10];
    const float* beta3 = (const float*)d_in[11];
    const float* W4 = (const float*)d_in[12];
    const float* b4 = (const float*)d_in[13];
    const float* g4 = (const float*)d_in[14];
    const float* beta4 = (const float*)d_in[15];
    const float* W5 = (const float*)d_in[16];
    const float* b5 = (const float*)d_in[17];
    float* out = (float*)d_out;

    const int n  = in_sizes[0] / 32;    // 50000
    const int nE = in_sizes[1];         // 800000
    const int nPad = 50176;             // 196 * 256
    const int nBlk = nPad / 256;        // 196

    // workspace layout (4-byte units)
    int*   wsi     = (int*)d_ws;
    int*   counts  = wsi;                         // 50176
    float* dinv    = (float*)(counts + nPad);     // 50176
    int*   row     = (int*)(dinv + nPad);         // 50176  (cursor -> row_end)
    int*   partial = row + nPad;                  // 256
    float* h1p     = (float*)(partial + 256);     // n*64
    float* h1      = h1p + (size_t)n * 64;        // n*64
    float* h2p     = h1 + (size_t)n * 64;         // n*128
    int*   csr_src = (int*)(h2p + (size_t)n * 128); // nE
    float* pooled  = (float*)(csr_src + nE);      // 64*128

    // 0) zero counts + pooled (must re-init every call)
    hipMemsetAsync(counts, 0, nPad * sizeof(int), stream);
    hipMemsetAsync(pooled, 0, 64 * 128 * sizeof(float), stream);

    // 1) CSR build: hist -> dinv, scan, fill
    k_hist<<<(nE + 255) / 256, 256, 0, stream>>>(edge_dst, counts, nE);
    k_dinv<<<(nPad + 255) / 256, 256, 0, stream>>>(counts, dinv, nPad);
    k_scan_block<<<nBlk, 256, 0, stream>>>(counts, row, partial, n);
    k_scan_partial<<<1, 256, 0, stream>>>(partial, nBlk);
    k_scan_add<<<nBlk, 256, 0, stream>>>(row, partial, n);
    k_fill<<<(nE + 255) / 256, 256, 0, stream>>>(edge_src, edge_dst, row, csr_src, nE);
    // after k_fill, row[d] == row_end[d]

    // 2) layer 1: 32 -> 64
    k_mm<32, 64, 4><<<(n + 3) / 4, 256, 0, stream>>>(x, W1, h1p, n);
    k_gather<64, false><<<(n * 16 + 255) / 256, 256, 0, stream>>>(
        h1p, dinv, row, counts, csr_src, b1, h1, nullptr, nullptr, n);

    // 3) layer 2: 64 -> 128
    k_mm<64, 128, 2><<<(n + 1) / 2, 256, 0, stream>>>(h1, W2, h2p, n);
    k_gather<128, true><<<(n * 32 + 255) / 256, 256, 0, stream>>>(
        h2p, dinv, row, counts, csr_src, b2, nullptr, batch, (unsigned*)pooled, n);

    // 4) MLP head + log_softmax
    k_head<<<64, 128, 0, stream>>>(pooled, W3, b3, g3, beta3, W4, b4, g4, beta4, W5, b5, out);
}

// Round 4
// 275.092 us; speedup vs baseline: 3.8562x; 1.6829x over previous
//
#include <hip/hip_runtime.h>
#include <hip/hip_bf16.h>

#define N_NODES_C 50000
#define N_EDGES_C 800000
#define N_GRAPHS_C 64

// ---------------- histogram of dst (int counts) ----------------
__global__ void k_hist(const int* __restrict__ dst, int* __restrict__ counts, int nE) {
    int e = blockIdx.x * blockDim.x + threadIdx.x;
    if (e >= nE) return;
    atomicAdd(&counts[dst[e]], 1);
}

__global__ void k_dinv(const int* __restrict__ counts, float* __restrict__ dinv, int n) {
    int i = blockIdx.x * blockDim.x + threadIdx.x;
    if (i >= n) return;
    dinv[i] = rsqrtf((float)counts[i] + 1.0f);
}

// ---------------- 3-kernel exclusive scan over counts -> row ----------------
__global__ void k_scan_block(const int* __restrict__ counts, int* __restrict__ row,
                             int* __restrict__ partial, int n) {
    __shared__ int s[256];
    int i = blockIdx.x * 256 + threadIdx.x;
    int v = (i < n) ? counts[i] : 0;
    s[threadIdx.x] = v;
    __syncthreads();
    for (int off = 1; off < 256; off <<= 1) {
        int x = (threadIdx.x >= off) ? s[threadIdx.x - off] : 0;
        __syncthreads();
        s[threadIdx.x] += x;
        __syncthreads();
    }
    if (i < n) row[i] = s[threadIdx.x] - v;          // exclusive
    if (threadIdx.x == 255) partial[blockIdx.x] = s[255];
}

__global__ void k_scan_partial(int* __restrict__ partial, int m) {
    __shared__ int s[256];
    int v = (threadIdx.x < m) ? partial[threadIdx.x] : 0;
    s[threadIdx.x] = v;
    __syncthreads();
    for (int off = 1; off < 256; off <<= 1) {
        int x = (threadIdx.x >= off) ? s[threadIdx.x - off] : 0;
        __syncthreads();
        s[threadIdx.x] += x;
        __syncthreads();
    }
    if (threadIdx.x < m) partial[threadIdx.x] = s[threadIdx.x] - v;   // exclusive
}

__global__ void k_scan_add(int* __restrict__ row, const int* __restrict__ partial, int n) {
    int i = blockIdx.x * 256 + threadIdx.x;
    if (i < n) row[i] += partial[blockIdx.x];
}

// ---------------- fill CSR: row[d] acts as cursor, ends at row_end ----------------
__global__ void k_fill(const int* __restrict__ src, const int* __restrict__ dst,
                       int* __restrict__ row, int* __restrict__ csr_src, int nE) {
    int e = blockIdx.x * blockDim.x + threadIdx.x;
    if (e >= nE) return;
    int d = dst[e];
    int p = atomicAdd(&row[d], 1);
    csr_src[p] = src[e];
}

// ---------------- pull aggregation on INPUT features (aggregate-then-transform) ----------
// OUT[d] = dinv[d] * ( sum_e X[s]*dinv[s] + X[d]*dinv[d] )
template<int C>
__global__ void k_gather(const float* __restrict__ X, const float* __restrict__ dinv,
                         const int* __restrict__ row_end, const int* __restrict__ counts,
                         const int* __restrict__ csr_src,
                         float* __restrict__ OUT, int n) {
    constexpr int LPN = C / 4;            // lanes per node (float4 per lane)
    constexpr int NPB = 256 / LPN;        // nodes per block
    const int node = blockIdx.x * NPB + threadIdx.x / LPN;
    const int lane = threadIdx.x % LPN;
    if (node >= n) return;
    const int end = row_end[node];
    const int start = end - counts[node];
    const float4* __restrict__ X4 = (const float4*)X;
    const float dd = dinv[node];
    float4 hs = X4[(size_t)node * LPN + lane];
    float4 acc;
    acc.x = hs.x * dd; acc.y = hs.y * dd; acc.z = hs.z * dd; acc.w = hs.w * dd;
    int j = start;
    // unroll-by-4: 8 independent loads in flight per iteration
    for (; j + 4 <= end; j += 4) {
        int s0 = csr_src[j + 0], s1 = csr_src[j + 1];
        int s2 = csr_src[j + 2], s3 = csr_src[j + 3];
        float e0 = dinv[s0], e1 = dinv[s1], e2 = dinv[s2], e3 = dinv[s3];
        float4 h0 = X4[(size_t)s0 * LPN + lane];
        float4 h1 = X4[(size_t)s1 * LPN + lane];
        float4 h2 = X4[(size_t)s2 * LPN + lane];
        float4 h3 = X4[(size_t)s3 * LPN + lane];
        acc.x = fmaf(h0.x, e0, acc.x); acc.y = fmaf(h0.y, e0, acc.y);
        acc.z = fmaf(h0.z, e0, acc.z); acc.w = fmaf(h0.w, e0, acc.w);
        acc.x = fmaf(h1.x, e1, acc.x); acc.y = fmaf(h1.y, e1, acc.y);
        acc.z = fmaf(h1.z, e1, acc.z); acc.w = fmaf(h1.w, e1, acc.w);
        acc.x = fmaf(h2.x, e2, acc.x); acc.y = fmaf(h2.y, e2, acc.y);
        acc.z = fmaf(h2.z, e2, acc.z); acc.w = fmaf(h2.w, e2, acc.w);
        acc.x = fmaf(h3.x, e3, acc.x); acc.y = fmaf(h3.y, e3, acc.y);
        acc.z = fmaf(h3.z, e3, acc.z); acc.w = fmaf(h3.w, e3, acc.w);
    }
    for (; j < end; ++j) {
        int s = csr_src[j];
        float e = dinv[s];
        float4 h = X4[(size_t)s * LPN + lane];
        acc.x = fmaf(h.x, e, acc.x); acc.y = fmaf(h.y, e, acc.y);
        acc.z = fmaf(h.z, e, acc.z); acc.w = fmaf(h.w, e, acc.w);
    }
    acc.x *= dd; acc.y *= dd; acc.z *= dd; acc.w *= dd;
    ((float4*)OUT)[(size_t)node * LPN + lane] = acc;
}

// ---------------- dense matmul H = relu(X @ W + b), optional fused pool ----------------
template<int CIN, int COUT, int RPB, bool POOL>
__global__ void k_mm(const float* __restrict__ X, const float* __restrict__ W,
                     const float* __restrict__ bias,
                     float* __restrict__ H, const int* __restrict__ batch,
                     unsigned* __restrict__ P, int n) {
    __shared__ float sW[CIN * COUT];
    __shared__ float sx[RPB][CIN];
    const int tid = threadIdx.x;
    for (int i = tid; i < CIN * COUT; i += RPB * COUT) sW[i] = W[i];
    for (int i = tid; i < RPB * CIN; i += RPB * COUT) {
        int rr = i / CIN, kk = i % CIN;
        int grow = blockIdx.x * RPB + rr;
        sx[rr][kk] = (grow < n) ? X[grow * CIN + kk] : 0.f;
    }
    __syncthreads();
    const int r = tid / COUT, c = tid % COUT;
    const int row = blockIdx.x * RPB + r;
    if (row >= n) return;
    float acc = 0.f;
#pragma unroll
    for (int k = 0; k < CIN; ++k) acc = fmaf(sx[r][k], sW[k * COUT + c], acc);
    float v = acc + bias[c];
    v = v > 0.f ? v : 0.f;
    if (POOL) {
        atomicMax(&P[(size_t)batch[row] * COUT + c], __float_as_uint(v));
    } else {
        H[(size_t)row * COUT + c] = v;
    }
}

// ---------------- MLP head + log_softmax: one block per graph ----------------
__global__ void k_head(const float* __restrict__ P,
                       const float* __restrict__ W3, const float* __restrict__ b3,
                       const float* __restrict__ g3, const float* __restrict__ beta3,
                       const float* __restrict__ W4, const float* __restrict__ b4,
                       const float* __restrict__ g4, const float* __restrict__ beta4,
                       const float* __restrict__ W5, const float* __restrict__ b5,
                       float* __restrict__ out) {
    __shared__ float sP[128];
    __shared__ float sz3[32];
    __shared__ float sz4[64];
    __shared__ float slg[10];
    __shared__ float slse;
    const int g = blockIdx.x, tid = threadIdx.x;   // 128 threads
    sP[tid] = P[g * 128 + tid];
    __syncthreads();
    const float bnscale = rsqrtf(1.0f + 1e-5f);

    if (tid < 32) {
        float a = 0.f;
#pragma unroll
        for (int k = 0; k < 128; ++k) a = fmaf(sP[k], W3[k * 32 + tid], a);
        a += b3[tid];
        a = a > 0.f ? a : 0.f;
        sz3[tid] = a * (g3[tid] * bnscale) + beta3[tid];
    }
    __syncthreads();
    if (tid < 64) {
        float a = 0.f;
#pragma unroll
        for (int k = 0; k < 32; ++k) a = fmaf(sz3[k], W4[k * 64 + tid], a);
        a += b4[tid];
        a = a > 0.f ? a : 0.f;
        sz4[tid] = a * (g4[tid] * bnscale) + beta4[tid];
    }
    __syncthreads();
    if (tid < 10) {
        float a = 0.f;
#pragma unroll
        for (int k = 0; k < 64; ++k) a = fmaf(sz4[k], W5[k * 10 + tid], a);
        slg[tid] = a + b5[tid];
    }
    __syncthreads();
    if (tid == 0) {
        float m = -1e30f;
#pragma unroll
        for (int j = 0; j < 10; ++j) m = fmaxf(m, slg[j]);
        float s = 0.f;
#pragma unroll
        for (int j = 0; j < 10; ++j) s += expf(slg[j] - m);
        slse = m + logf(s);
    }
    __syncthreads();
    if (tid < 10) out[g * 10 + tid] = slg[tid] - slse;
}

extern "C" void kernel_launch(void* const* d_in, const int* in_sizes, int n_in,
                              void* d_out, int out_size, void* d_ws, size_t ws_size,
                              hipStream_t stream) {
    const float* x        = (const float*)d_in[0];
    const int*   edge_src = (const int*)d_in[1];
    const int*   edge_dst = (const int*)d_in[2];
    const int*   batch    = (const int*)d_in[3];
    const float* W1 = (const float*)d_in[4];
    const float* b1 = (const float*)d_in[5];
    const float* W2 = (const float*)d_in[6];
    const float* b2 = (const float*)d_in[7];
    const float* W3 = (const float*)d_in[8];
    const float* b3 = (const float*)d_in[9];
    const float* g3 = (const float*)d_in[10];
    const float* beta3 = (const float*)d_in[11];
    const float* W4 = (const float*)d_in[12];
    const float* b4 = (const float*)d_in[13];
    const float* g4 = (const float*)d_in[14];
    const float* beta4 = (const float*)d_in[15];
    const float* W5 = (const float*)d_in[16];
    const float* b5 = (const float*)d_in[17];
    float* out = (float*)d_out;

    const int n  = in_sizes[0] / 32;    // 50000
    const int nE = in_sizes[1];         // 800000
    const int nPad = 50176;             // 196 * 256
    const int nBlk = nPad / 256;        // 196

    // workspace layout (4-byte units)
    int*   wsi     = (int*)d_ws;
    int*   counts  = wsi;                           // 50176
    float* dinv    = (float*)(counts + nPad);       // 50176
    int*   row     = (int*)(dinv + nPad);           // 50176  (cursor -> row_end)
    int*   partial = row + nPad;                    // 256
    float* aggX    = (float*)(partial + 256);       // n*32
    float* h1      = aggX + (size_t)n * 32;         // n*64
    float* agg2    = h1 + (size_t)n * 64;           // n*64
    int*   csr_src = (int*)(agg2 + (size_t)n * 64); // nE
    float* pooled  = (float*)(csr_src + nE);        // 64*128

    // 0) zero counts + pooled (must re-init every call)
    hipMemsetAsync(counts, 0, nPad * sizeof(int), stream);
    hipMemsetAsync(pooled, 0, 64 * 128 * sizeof(float), stream);

    // 1) CSR build: hist -> dinv, scan, fill
    k_hist<<<(nE + 255) / 256, 256, 0, stream>>>(edge_dst, counts, nE);
    k_dinv<<<(nPad + 255) / 256, 256, 0, stream>>>(counts, dinv, nPad);
    k_scan_block<<<nBlk, 256, 0, stream>>>(counts, row, partial, n);
    k_scan_partial<<<1, 256, 0, stream>>>(partial, nBlk);
    k_scan_add<<<nBlk, 256, 0, stream>>>(row, partial, n);
    k_fill<<<(nE + 255) / 256, 256, 0, stream>>>(edge_src, edge_dst, row, csr_src, nE);
    // after k_fill, row[d] == row_end[d]

    // 2) layer 1: aggregate x (C=32), then h1 = relu(aggX @ W1 + b1)
    k_gather<32><<<(n * 8 + 255) / 256, 256, 0, stream>>>(x, dinv, row, counts, csr_src, aggX, n);
    k_mm<32, 64, 4, false><<<(n + 3) / 4, 256, 0, stream>>>(aggX, W1, b1, h1, nullptr, nullptr, n);

    // 3) layer 2: aggregate h1 (C=64), then pooled = segmax(relu(agg2 @ W2 + b2))
    k_gather<64><<<(n * 16 + 255) / 256, 256, 0, stream>>>(h1, dinv, row, counts, csr_src, agg2, n);
    k_mm<64, 128, 2, true><<<(n + 1) / 2, 256, 0, stream>>>(agg2, W2, b2, nullptr, batch, (unsigned*)pooled, n);

    // 4) MLP head + log_softmax
    k_head<<<64, 128, 0, stream>>>(pooled, W3, b3, g3, beta3, W4, b4, g4, beta4, W5, b5, out);
}